// Round 2
// baseline (397.251 us; speedup 1.0000x reference)
//
#include <hip/hip_runtime.h>

#define IMG    224
#define NPIX   (IMG * IMG)       // 50176
#define NELEM  (NPIX * 3)        // 150528
#define KSEL   12544             // 0.25 * IMG * IMG
#define NBINS  4096
#define NVEC4  (NELEM / 4)       // 37632 float4 per sample

// ---- K1: histogram ----
#define K1_CHUNKS 4
#define K1_BLOCK  256
#define K1_V4     (NVEC4 / K1_CHUNKS)   // 9408 float4 per block

// ---- K3: classify + apply ----
#define CH        8                     // chunks per sample
#define PIX_PER   (NPIX / CH)           // 6272 pixels per chunk
#define QUADS_PER (PIX_PER / 4)         // 1568
#define MWORDS    (PIX_PER / 32)        // 196 mask words
#define EV4_PER   (PIX_PER * 3 / 4)     // 4704 float4 of data per chunk

#define CAP 512                          // candidate capacity per sample (mean ~37)

// ============================================================ K1: histogram
__global__ __launch_bounds__(K1_BLOCK) void k1_hist(
    const float* __restrict__ grad, unsigned int* __restrict__ hist)
{
    const int s     = blockIdx.x >> 2;
    const int chunk = blockIdx.x & 3;
    const float4* g4 = (const float4*)(grad + (size_t)s * NELEM);

    __shared__ unsigned int h[NBINS];
    for (int i = threadIdx.x; i < NBINS; i += K1_BLOCK) h[i] = 0u;
    __syncthreads();

    const int beg = chunk * K1_V4, end = beg + K1_V4;
    for (int i = beg + threadIdx.x; i < end; i += K1_BLOCK) {
        float4 v = g4[i];
        atomicAdd(&h[min((int)(v.x * 4096.0f), NBINS - 1)], 1u);
        atomicAdd(&h[min((int)(v.y * 4096.0f), NBINS - 1)], 1u);
        atomicAdd(&h[min((int)(v.z * 4096.0f), NBINS - 1)], 1u);
        atomicAdd(&h[min((int)(v.w * 4096.0f), NBINS - 1)], 1u);
    }
    __syncthreads();

    unsigned int* gh = hist + (size_t)s * NBINS;
    for (int i = threadIdx.x; i < NBINS; i += K1_BLOCK)
        if (h[i]) atomicAdd(&gh[i], h[i]);
}

// ============================================================ K2: suffix scan
__global__ __launch_bounds__(1024) void k2_scan(
    const unsigned int* __restrict__ hist,
    uint2* __restrict__ thr, unsigned int* __restrict__ candcnt)
{
    const int s   = blockIdx.x;
    const int tid = threadIdx.x;
    const unsigned int* h = hist + (size_t)s * NBINS;

    unsigned int h0 = h[4 * tid], h1 = h[4 * tid + 1];
    unsigned int h2 = h[4 * tid + 2], h3 = h[4 * tid + 3];
    const unsigned int gsum = h0 + h1 + h2 + h3;

    const int lane = tid & 63, w = tid >> 6;
    unsigned int v = gsum;
    #pragma unroll
    for (int off = 1; off < 64; off <<= 1) {
        unsigned int u = __shfl_down(v, off, 64);
        if (lane + off < 64) v += u;          // wave-local suffix sum
    }
    __shared__ unsigned int wtot[16];
    if (lane == 0) wtot[w] = v;               // wave total
    __syncthreads();
    unsigned int tail = 0;
    for (int i = w + 1; i < 16; ++i) tail += wtot[i];

    const unsigned int suffix     = v + tail;        // sum of groups [tid..1023]
    const unsigned int suffixNext = suffix - gsum;   // sum of groups [tid+1..1023]

    if (suffix >= KSEL && suffixNext < KSEL) {
        unsigned int cum = suffixNext;
        unsigned int hh[4] = {h0, h1, h2, h3};
        for (int i = 3; i >= 0; --i) {
            cum += hh[i];
            if (cum >= KSEL) {
                thr[s] = make_uint2((unsigned)(4 * tid + i),
                                    (unsigned)(KSEL - (cum - hh[i])));
                break;
            }
        }
    }
    if (tid == 0) candcnt[s] = 0u;
}

// ============================================================ K3: classify + apply
__global__ __launch_bounds__(256) void k3_apply(
    const float* __restrict__ data, const float* __restrict__ grad,
    const uint2* __restrict__ thr,
    unsigned int* __restrict__ candcnt,
    unsigned int* __restrict__ candkey, unsigned int* __restrict__ candidx,
    float* __restrict__ out)
{
    const int s     = blockIdx.x >> 3;      // / CH
    const int chunk = blockIdx.x & 7;
    const int p0    = chunk * PIX_PER;

    const uint2 t  = thr[s];
    const float t0 = (float)t.x * (1.0f / 4096.0f);        // exact
    const float t1 = (float)(t.x + 1) * (1.0f / 4096.0f);  // exact

    __shared__ unsigned int mask[MWORDS];
    for (int i = threadIdx.x; i < MWORDS; i += 256) mask[i] = 0u;
    __syncthreads();

    const float4* g4 = (const float4*)(grad + (size_t)s * NELEM);
    unsigned int* ck = candkey + (size_t)s * CAP;
    unsigned int* ci = candidx + (size_t)s * CAP;

    for (int q = threadIdx.x; q < QUADS_PER; q += 256) {
        const int p = p0 + 4 * q;                 // global pixel of lane's quad
        float4 a = g4[p >> 2];                    // channel-plane 0
        float4 b = g4[(p + NPIX) >> 2];           // plane 1
        float4 c = g4[(p + 2 * NPIX) >> 2];       // plane 2
        float av[4] = {a.x, a.y, a.z, a.w};
        float bv[4] = {b.x, b.y, b.z, b.w};
        float cv[4] = {c.x, c.y, c.z, c.w};
        unsigned int m = 0;
        #pragma unroll
        for (int j = 0; j < 4; ++j) {
            if ((av[j] >= t1) || (bv[j] >= t1) || (cv[j] >= t1)) m |= (1u << j);
            // bin == B1 candidates -> global list (rare: ~37 / 150528 elems)
            if (av[j] >= t0 && av[j] < t1) {
                unsigned int cc = atomicAdd(&candcnt[s], 1u);
                if (cc < CAP) { ck[cc] = __float_as_uint(av[j]); ci[cc] = (unsigned)(p + j); }
            }
            if (bv[j] >= t0 && bv[j] < t1) {
                unsigned int cc = atomicAdd(&candcnt[s], 1u);
                if (cc < CAP) { ck[cc] = __float_as_uint(bv[j]); ci[cc] = (unsigned)(NPIX + p + j); }
            }
            if (cv[j] >= t0 && cv[j] < t1) {
                unsigned int cc = atomicAdd(&candcnt[s], 1u);
                if (cc < CAP) { ck[cc] = __float_as_uint(cv[j]); ci[cc] = (unsigned)(2 * NPIX + p + j); }
            }
        }
        if (m) atomicOr(&mask[q >> 3], m << ((4 * q) & 31));
    }
    __syncthreads();

    // stream data -> out for this chunk's element range, applying LDS mask
    const float4* d4 = (const float4*)(data + (size_t)s * NELEM + (size_t)3 * p0);
    float4*       o4 = (float4*)(out  + (size_t)s * NELEM + (size_t)3 * p0);
    for (int i = threadIdx.x; i < EV4_PER; i += 256) {
        float4 v = d4[i];
        const int e = 4 * i;                       // chunk-local element offset
        const int lp0 = e / 3, lp1 = (e + 1) / 3, lp2 = (e + 2) / 3, lp3 = (e + 3) / 3;
        if ((mask[lp0 >> 5] >> (lp0 & 31)) & 1u) v.x = 0.0f;
        if ((mask[lp1 >> 5] >> (lp1 & 31)) & 1u) v.y = 0.0f;
        if ((mask[lp2 >> 5] >> (lp2 & 31)) & 1u) v.z = 0.0f;
        if ((mask[lp3 >> 5] >> (lp3 & 31)) & 1u) v.w = 0.0f;
        o4[i] = v;
    }
}

// ============================================================ K4: exact tie ranking
__global__ __launch_bounds__(64) void k4_ties(
    const uint2* __restrict__ thr, const unsigned int* __restrict__ candcnt,
    const unsigned int* __restrict__ candkey, const unsigned int* __restrict__ candidx,
    float* __restrict__ out)
{
    const int s = blockIdx.x;
    const unsigned int n = min(candcnt[s], (unsigned int)CAP);
    const unsigned int r = thr[s].y;
    const unsigned int* ck = candkey + (size_t)s * CAP;
    const unsigned int* ci = candidx + (size_t)s * CAP;

    __shared__ unsigned int k_[CAP], i_[CAP];
    for (unsigned int i = threadIdx.x; i < n; i += 64) { k_[i] = ck[i]; i_[i] = ci[i]; }
    __syncthreads();

    float* o = out + (size_t)s * NELEM;
    for (unsigned int j = threadIdx.x; j < n; j += 64) {
        const unsigned int kj = k_[j], ij = i_[j];
        unsigned int rank = 0;
        for (unsigned int i = 0; i < n; ++i)
            rank += (k_[i] > kj) || (k_[i] == kj && i_[i] < ij);
        if (rank < r) {   // selected: (value desc, index asc) — jax.lax.top_k order
            const int p = (int)(ij % NPIX);
            o[3 * p] = 0.0f; o[3 * p + 1] = 0.0f; o[3 * p + 2] = 0.0f;
        }
    }
}

// ============================================================ fallback (round-1 monolith)
#define MAXCAND 2048
#define NMASKW (NPIX / 32)
#define BLOCK  1024

__global__ __launch_bounds__(BLOCK) void masked_model_kernel(
    const float* __restrict__ data,
    const float* __restrict__ grad,
    float* __restrict__ out)
{
    const int b   = blockIdx.x;
    const int tid = threadIdx.x;

    const float* g = grad + (size_t)b * NELEM;
    const float* d = data + (size_t)b * NELEM;
    float*       o = out  + (size_t)b * NELEM;

    __shared__ unsigned int hist[NBINS];
    __shared__ unsigned int suffixP[BLOCK + 1];
    __shared__ unsigned int mask[NMASKW];
    __shared__ unsigned int candkey[MAXCAND];
    __shared__ unsigned int candidx[MAXCAND];
    __shared__ unsigned int candcnt;
    __shared__ int sB1;
    __shared__ unsigned int sR;

    for (int i = tid; i < NBINS; i += BLOCK) hist[i] = 0u;
    for (int i = tid; i < NMASKW; i += BLOCK) mask[i] = 0u;
    if (tid == 0) { candcnt = 0u; suffixP[BLOCK] = 0u; }
    __syncthreads();

    const float4* g4 = (const float4*)g;
    for (int i = tid; i < NVEC4; i += BLOCK) {
        float4 v = g4[i];
        atomicAdd(&hist[min((int)(v.x * 4096.0f), NBINS - 1)], 1u);
        atomicAdd(&hist[min((int)(v.y * 4096.0f), NBINS - 1)], 1u);
        atomicAdd(&hist[min((int)(v.z * 4096.0f), NBINS - 1)], 1u);
        atomicAdd(&hist[min((int)(v.w * 4096.0f), NBINS - 1)], 1u);
    }
    __syncthreads();

    {
        unsigned int sv = hist[4 * tid] + hist[4 * tid + 1]
                        + hist[4 * tid + 2] + hist[4 * tid + 3];
        suffixP[tid] = sv;
        __syncthreads();
        for (int off = 1; off < BLOCK; off <<= 1) {
            unsigned int v = suffixP[tid];
            if (tid + off < BLOCK) v += suffixP[tid + off];
            __syncthreads();
            suffixP[tid] = v;
            __syncthreads();
        }
    }
    {
        unsigned int a  = suffixP[tid];
        unsigned int nx = suffixP[tid + 1];
        if (a >= KSEL && nx < KSEL) {
            unsigned int cum = nx;
            for (int i = 3; i >= 0; --i) {
                unsigned int h = hist[4 * tid + i];
                cum += h;
                if (cum >= KSEL) { sB1 = 4 * tid + i; sR = KSEL - (cum - h); break; }
            }
        }
    }
    __syncthreads();

    {
        const int B1 = sB1;
        for (int i = tid; i < NVEC4; i += BLOCK) {
            float4 v = g4[i];
            int base = 4 * i;
            float vv[4] = {v.x, v.y, v.z, v.w};
            #pragma unroll
            for (int c = 0; c < 4; ++c) {
                int bin = min((int)(vv[c] * 4096.0f), NBINS - 1);
                if (bin > B1) {
                    int p = (base + c) % NPIX;
                    atomicOr(&mask[p >> 5], 1u << (p & 31));
                } else if (bin == B1) {
                    unsigned int c2 = atomicAdd(&candcnt, 1u);
                    if (c2 < MAXCAND) {
                        candkey[c2] = __float_as_uint(vv[c]);
                        candidx[c2] = (unsigned int)(base + c);
                    }
                }
            }
        }
    }
    __syncthreads();

    {
        unsigned int n = candcnt < MAXCAND ? candcnt : MAXCAND;
        unsigned int r = sR;
        for (unsigned int j = tid; j < n; j += BLOCK) {
            unsigned int kj = candkey[j];
            unsigned int ij = candidx[j];
            unsigned int rank = 0;
            for (unsigned int i = 0; i < n; ++i) {
                unsigned int ki = candkey[i];
                rank += (ki > kj) || (ki == kj && candidx[i] < ij);
            }
            if (rank < r) {
                int p = (int)(ij % NPIX);
                atomicOr(&mask[p >> 5], 1u << (p & 31));
            }
        }
    }
    __syncthreads();

    {
        const float4* d4 = (const float4*)d;
        float4*       o4 = (float4*)o;
        for (int i = tid; i < NVEC4; i += BLOCK) {
            float4 v = d4[i];
            int e = 4 * i;
            int p0 = e / 3, p1 = (e + 1) / 3, p2 = (e + 2) / 3, p3 = (e + 3) / 3;
            if ((mask[p0 >> 5] >> (p0 & 31)) & 1u) v.x = 0.0f;
            if ((mask[p1 >> 5] >> (p1 & 31)) & 1u) v.y = 0.0f;
            if ((mask[p2 >> 5] >> (p2 & 31)) & 1u) v.z = 0.0f;
            if ((mask[p3 >> 5] >> (p3 & 31)) & 1u) v.w = 0.0f;
            o4[i] = v;
        }
    }
}

// ============================================================ launch
extern "C" void kernel_launch(void* const* d_in, const int* in_sizes, int n_in,
                              void* d_out, int out_size, void* d_ws, size_t ws_size,
                              hipStream_t stream) {
    const float* data = (const float*)d_in[0];   // [B, 224, 224, 3] fp32
    const float* grad = (const float*)d_in[1];   // [B, 150528] fp32
    float* out = (float*)d_out;

    const int B = in_sizes[0] / NELEM;

    const size_t histB = (size_t)B * NBINS * sizeof(unsigned int);  // 4.19 MB @ B=256
    const size_t thrB  = (size_t)B * sizeof(uint2);
    const size_t cntB  = (size_t)B * sizeof(unsigned int);
    // pad cnt region so candidate arrays stay 8-aligned
    const size_t cntPad = (cntB + 7) & ~(size_t)7;
    const size_t keyB  = (size_t)B * CAP * sizeof(unsigned int);

    char* p = (char*)d_ws;
    unsigned int* hist = (unsigned int*)p;  p += histB;
    uint2*        thr  = (uint2*)p;         p += thrB;
    unsigned int* cnt  = (unsigned int*)p;  p += cntPad;
    unsigned int* ckey = (unsigned int*)p;  p += keyB;
    unsigned int* cidx = (unsigned int*)p;  p += keyB;
    const size_t need = (size_t)(p - (char*)d_ws);

    if (ws_size >= need) {
        hipMemsetAsync(hist, 0, histB, stream);
        k1_hist<<<B * K1_CHUNKS, K1_BLOCK, 0, stream>>>(grad, hist);
        k2_scan<<<B, 1024, 0, stream>>>(hist, thr, cnt);
        k3_apply<<<B * CH, 256, 0, stream>>>(data, grad, thr, cnt, ckey, cidx, out);
        k4_ties<<<B, 64, 0, stream>>>(thr, cnt, ckey, cidx, out);
    } else {
        // scratch too small: proven single-kernel path
        masked_model_kernel<<<B, BLOCK, 0, stream>>>(data, grad, out);
    }
}